// Round 6
// baseline (527.961 us; speedup 1.0000x reference)
//
#include <hip/hip_runtime.h>

#define B_SZ 256
#define S_LEN 512
#define NT 128
#define PAD 127
#define LN2F 0.69314718055994530942f
#define RENORM 0x1p-62f

typedef float v2f __attribute__((ext_vector_type(2)));

__device__ __forceinline__ float bcastf(float v, int k) {
    return __uint_as_float((unsigned)__builtin_amdgcn_readlane((int)__float_as_uint(v), k));
}

// Barrier draining only LDS (lgkmcnt), NOT vmcnt — emission prefetch loads
// stay in flight across steps.
__device__ __forceinline__ void lds_barrier() {
    asm volatile("s_waitcnt lgkmcnt(0)\n\ts_barrier" ::: "memory");
}

// FOUR independent batch-chains interleaved in the SAME 4 waves (r0+r5
// calibration: per-chain serial work W~456cyc, per-barrier fixed ~469cyc;
// interleaving C chains in one stream pays the fixed cost once per C
// chain-steps). Per chain, r0's proven engine: K-split, readlane broadcast,
// v2f pk-FMA. Each wave maintains only ITS OWN 32-wide alpha k-slice
// (lanes 0-31): it only ever broadcasts that slice, so the post-barrier
// reduce is 4x ds_read_b32 (2-way broadcast, free) + 3 scalar adds.
__global__ __launch_bounds__(256, 1) void crf_fused(
    const float* __restrict__ em,      // (B,S,T)
    const int*   __restrict__ tags,    // (B,S)
    const float* __restrict__ startT,  // (T)
    const float* __restrict__ endT,    // (T)
    const float* __restrict__ trans,   // (T,T)
    float* __restrict__ out)
{
    const int tid = threadIdx.x;
    const int w   = tid >> 6;          // wave 0..3
    const int l   = tid & 63;          // lane
    const int la  = l & 31;            // lane within half-wave
    const int b0  = blockIdx.x * 4;    // first batch of this block

    __shared__ float bufp[4][2][4][NT];   // [chain][parity][srcwave][state]
    __shared__ float maskv[4][S_LEN];     // [chain][step]
    __shared__ float aF[4][NT];           // final alpha gather
    __shared__ float nred[4][4];          // [chain][wave]
    __shared__ int   cred[4][4];

    const float* em_b0 = em + (size_t)(b0 + 0) * S_LEN * NT;
    const float* em_b1 = em + (size_t)(b0 + 1) * S_LEN * NT;
    const float* em_b2 = em + (size_t)(b0 + 2) * S_LEN * NT;
    const float* em_b3 = em + (size_t)(b0 + 3) * S_LEN * NT;

    // ---- stage per-step masks + numerator/count, per chain ----
    for (int c = 0; c < 4; ++c) {
        const int*   tg  = tags + (size_t)(b0 + c) * S_LEN;
        const float* emc = em + (size_t)(b0 + c) * S_LEN * NT;
        for (int q = tid; q < S_LEN; q += 256)
            maskv[c][q] = (tg[q] != PAD) ? 1.0f : 0.0f;
        float numSum = 0.f;
        int   cnt    = 0;
        #pragma unroll
        for (int q = 0; q < 2; ++q) {
            int t  = 64 * (2 * w + q) + l;
            int tv = tg[t];
            cnt += (tv != PAD) ? 1 : 0;
            float emg = emc[(size_t)t * NT + tv];
            if (t == 0) {
                numSum += startT[tv] + emg;
            } else {
                int tp = tg[t - 1];
                float v = trans[tp * NT + tv] + emg;
                numSum += (tv != PAD) ? v : 0.f;
            }
        }
        #pragma unroll
        for (int off = 32; off > 0; off >>= 1) {
            numSum += __shfl_down(numSum, off, 64);
            cnt    += __shfl_down(cnt, off, 64);
        }
        if (l == 0) { nred[c][w] = numSum; cred[c][w] = cnt; }
    }

    // ---- column registers for this wave's K-slice (shared by all chains) ----
    const int k0 = 32 * w;
    v2f col[32];
    #pragma unroll
    for (int i = 0; i < 32; ++i) {
        col[i].x = __expf(trans[(k0 + i) * NT + l]);
        col[i].y = __expf(trans[(k0 + i) * NT + 64 + l]);
    }

    // ---- alpha_0 k-slices (lanes 0-31 hold slice; 32-63 duplicate) ----
    float aS0 = __expf(startT[k0 + la] + em_b0[k0 + la]);
    float aS1 = __expf(startT[k0 + la] + em_b1[k0 + la]);
    float aS2 = __expf(startT[k0 + la] + em_b2[k0 + la]);
    float aS3 = __expf(startT[k0 + la] + em_b3[k0 + la]);

    // ---- em pipeline, depth 2 per chain: slot A = odd t, slot B = even t ----
    float e0Ax = em_b0[1 * NT + l], e0Ay = em_b0[1 * NT + 64 + l];
    float e1Ax = em_b1[1 * NT + l], e1Ay = em_b1[1 * NT + 64 + l];
    float e2Ax = em_b2[1 * NT + l], e2Ay = em_b2[1 * NT + 64 + l];
    float e3Ax = em_b3[1 * NT + l], e3Ay = em_b3[1 * NT + 64 + l];
    float e0Bx = em_b0[2 * NT + l], e0By = em_b0[2 * NT + 64 + l];
    float e1Bx = em_b1[2 * NT + l], e1By = em_b1[2 * NT + 64 + l];
    float e2Bx = em_b2[2 * NT + l], e2By = em_b2[2 * NT + 64 + l];
    float e3Bx = em_b3[2 * NT + l], e3By = em_b3[2 * NT + 64 + l];

    __syncthreads();   // maskv + nred visible; one-time full barrier

// FMA + partial-write for chain C at step parity PAR (r0 engine verbatim).
#define FMAW(C, EX, EY, PAR)                                                 \
  {                                                                          \
    float e0_ = __expf(EX);                                                  \
    float e1_ = __expf(EY);                                                  \
    float sreg_ = aS##C;                                                     \
    v2f a0_ = {0.f,0.f}, a1_ = {0.f,0.f}, a2_ = {0.f,0.f}, a3_ = {0.f,0.f};  \
    _Pragma("unroll")                                                        \
    for (int i_ = 0; i_ < 32; i_ += 4) {                                     \
      float s0_ = bcastf(sreg_, i_);                                         \
      float s1_ = bcastf(sreg_, i_ + 1);                                     \
      float s2_ = bcastf(sreg_, i_ + 2);                                     \
      float s3_ = bcastf(sreg_, i_ + 3);                                     \
      a0_ += (v2f){s0_, s0_} * col[i_];                                      \
      a1_ += (v2f){s1_, s1_} * col[i_ + 1];                                  \
      a2_ += (v2f){s2_, s2_} * col[i_ + 2];                                  \
      a3_ += (v2f){s3_, s3_} * col[i_ + 3];                                  \
    }                                                                        \
    v2f p_ = (a0_ + a1_) + (a2_ + a3_);                                      \
    p_.x *= e0_;  p_.y *= e1_;           /* fold exp(em) */                  \
    bufp[C][PAR][w][l]      = p_.x;                                          \
    bufp[C][PAR][w][64 + l] = p_.y;                                          \
  }

// Post-barrier slice reduce for chain C: this wave's 32 k-values only.
#define RED(C, PAR, MV, RN)                                                  \
  {                                                                          \
    float x0_ = bufp[C][PAR][0][k0 + la];                                    \
    float x1_ = bufp[C][PAR][1][k0 + la];                                    \
    float x2_ = bufp[C][PAR][2][k0 + la];                                    \
    float x3_ = bufp[C][PAR][3][k0 + la];                                    \
    float s_  = (x0_ + x1_) + (x2_ + x3_);                                   \
    aS##C = ((MV) != 0.0f) ? s_ : aS##C;                                     \
    if (RN) aS##C *= RENORM;                                                 \
  }

// One iteration: advance ALL 4 chains one step t. SL is A (odd t) or B
// (even t). One barrier total; em loads for t+2 reload slot SL.
#define STEP(SL, T, RN)                                                      \
  {                                                                          \
    const int t_   = (T);                                                    \
    const int par_ = t_ & 1;                                                 \
    int   tn_ = (t_ + 2 < S_LEN) ? t_ + 2 : S_LEN - 1;                       \
    float mv0_ = maskv[0][t_], mv1_ = maskv[1][t_];                          \
    float mv2_ = maskv[2][t_], mv3_ = maskv[3][t_];                          \
    float n0x_ = em_b0[(size_t)tn_ * NT + l], n0y_ = em_b0[(size_t)tn_ * NT + 64 + l]; \
    float n1x_ = em_b1[(size_t)tn_ * NT + l], n1y_ = em_b1[(size_t)tn_ * NT + 64 + l]; \
    float n2x_ = em_b2[(size_t)tn_ * NT + l], n2y_ = em_b2[(size_t)tn_ * NT + 64 + l]; \
    float n3x_ = em_b3[(size_t)tn_ * NT + l], n3y_ = em_b3[(size_t)tn_ * NT + 64 + l]; \
    FMAW(0, e0##SL##x, e0##SL##y, par_)                                      \
    FMAW(1, e1##SL##x, e1##SL##y, par_)                                      \
    FMAW(2, e2##SL##x, e2##SL##y, par_)                                      \
    FMAW(3, e3##SL##x, e3##SL##y, par_)                                      \
    e0##SL##x = n0x_; e0##SL##y = n0y_;                                      \
    e1##SL##x = n1x_; e1##SL##y = n1y_;                                      \
    e2##SL##x = n2x_; e2##SL##y = n2y_;                                      \
    e3##SL##x = n3x_; e3##SL##y = n3y_;                                      \
    lds_barrier();                                                           \
    RED(0, par_, mv0_, RN)                                                   \
    RED(1, par_, mv1_, RN)                                                   \
    RED(2, par_, mv2_, RN)                                                   \
    RED(3, par_, mv3_, RN)                                                   \
  }

    // chunk 0: t = 1..7 (slot A=odd, B=even)
    STEP(A, 1, false) STEP(B, 2, false) STEP(A, 3, false) STEP(B, 4, false)
    STEP(A, 5, false) STEP(B, 6, false) STEP(A, 7, false)

    // chunks 1..63: t = 8c .. 8c+7 ; renorm at t = 8c (63 renorms total)
    for (int c = 1; c < 64; ++c) {
        const int t0 = c * 8;
        STEP(B, t0,     true)
        STEP(A, t0 + 1, false) STEP(B, t0 + 2, false) STEP(A, t0 + 3, false)
        STEP(B, t0 + 4, false) STEP(A, t0 + 5, false) STEP(B, t0 + 6, false)
        STEP(A, t0 + 7, false)
    }
#undef STEP
#undef FMAW
#undef RED

    // ---- gather final alpha slices (mask-correct), then wave c -> chain c ----
    if (l < 32) {
        aF[0][k0 + la] = aS0;
        aF[1][k0 + la] = aS1;
        aF[2][k0 + la] = aS2;
        aF[3][k0 + la] = aS3;
    }
    __syncthreads();

    {
        const int* tgw = tags + (size_t)(b0 + w) * S_LEN;
        float ax = aF[w][l];
        float ay = aF[w][64 + l];
        float pe = ax * __expf(endT[l]) + ay * __expf(endT[64 + l]);
        #pragma unroll
        for (int off = 32; off > 0; off >>= 1)
            pe += __shfl_down(pe, off, 64);
        if (l == 0) {
            int   cT   = (cred[w][0] + cred[w][1]) + (cred[w][2] + cred[w][3]);
            int   last = tgw[cT - 1];
            float num  = (nred[w][0] + nred[w][1]) + (nred[w][2] + nred[w][3])
                         + endT[last];
            float den  = 63.0f * 62.0f * LN2F + logf(pe);
            atomicAdd(out, (num - den) * (1.0f / (float)B_SZ));
        }
    }
}

extern "C" void kernel_launch(void* const* d_in, const int* in_sizes, int n_in,
                              void* d_out, int out_size, void* d_ws, size_t ws_size,
                              hipStream_t stream) {
    const float* em     = (const float*)d_in[0];
    const int*   tags   = (const int*)d_in[1];
    const float* startT = (const float*)d_in[2];
    const float* endT   = (const float*)d_in[3];
    const float* trans  = (const float*)d_in[4];
    float* out = (float*)d_out;

    hipMemsetAsync(out, 0, sizeof(float), stream);
    crf_fused<<<B_SZ / 4, 256, 0, stream>>>(em, tags, startT, endT, trans, out);
}

// Round 7
// 270.358 us; speedup vs baseline: 1.9528x; 1.9528x over previous
//
#include <hip/hip_runtime.h>

#define B_SZ 256
#define S_LEN 512
#define NT 128
#define PAD 127
#define LN2F 0.69314718055994530942f
#define RENORM 0x1p-62f

typedef float v2f __attribute__((ext_vector_type(2)));

__device__ __forceinline__ float bcastf(float v, int k) {
    return __uint_as_float((unsigned)__builtin_amdgcn_readlane((int)__float_as_uint(v), k));
}

// Barrier draining only LDS (lgkmcnt), NOT vmcnt — emission prefetch loads
// stay in flight across steps.
__device__ __forceinline__ void lds_barrier() {
    asm volatile("s_waitcnt lgkmcnt(0)\n\ts_barrier" ::: "memory");
}

// One block per batch, TWO waves, K-split 64 each (r0/r5/r6 calibration:
// T = fixed(469, 4-wave) + W(456); this cuts both).
// Wave w owns alpha-half [64w, 64w+64) in register aO (lane i = alpha[64w+i])
// — exactly its k-slice, so readlane broadcasts are intra-wave. Each lane
// accumulates BOTH j-halves via v_pk_fma (col[i] = {expT[k][l], expT[k][64+l]},
// 128 VGPRs). Cross-wave traffic per step: ship ONE raw partial float/lane
// (xchg write), read the other wave's, add, fold exp(em[own half]) AFTER
// combine (so only 1 em float + 1 exp per lane per step), mask-select, renorm.
// One 2-wave barrier per step; parity double-buffer makes it race-free.
__global__ __launch_bounds__(128, 1) void crf_fused(
    const float* __restrict__ em,      // (B,S,T)
    const int*   __restrict__ tags,    // (B,S)
    const float* __restrict__ startT,  // (T)
    const float* __restrict__ endT,    // (T)
    const float* __restrict__ trans,   // (T,T)
    float* __restrict__ out)
{
    const int b   = blockIdx.x;
    const int tid = threadIdx.x;
    const int w   = tid >> 6;          // wave 0..1
    const int l   = tid & 63;          // lane
    const int hw  = 64 * w;            // this wave's half/k-slice base

    __shared__ float xchg[2][2][64];   // [parity][dst wave][lane]
    __shared__ float maskv[S_LEN];     // per-step mask as float
    __shared__ float aF[NT];           // final alpha gather
    __shared__ float nred[2];
    __shared__ int   cred[2];

    const float* em_b = em + (size_t)b * S_LEN * NT;
    const int*   tg_b = tags + (size_t)b * S_LEN;

    // ---- stage per-step masks ----
    for (int q = tid; q < S_LEN; q += 128)
        maskv[q] = (tg_b[q] != PAD) ? 1.0f : 0.0f;

    // ---- numerator partial + valid count (wave w covers chunks 4w..4w+3) ----
    float numSum = 0.f;
    int   cnt    = 0;
    #pragma unroll
    for (int q = 0; q < 4; ++q) {
        int t  = 64 * (4 * w + q) + l;
        int tv = tg_b[t];
        cnt += (tv != PAD) ? 1 : 0;
        float emg = em_b[(size_t)t * NT + tv];
        if (t == 0) {
            numSum += startT[tv] + emg;
        } else {
            int tp = tg_b[t - 1];
            float v = trans[tp * NT + tv] + emg;
            numSum += (tv != PAD) ? v : 0.f;
        }
    }
    #pragma unroll
    for (int off = 32; off > 0; off >>= 1) {
        numSum += __shfl_down(numSum, off, 64);
        cnt    += __shfl_down(cnt, off, 64);
    }
    if (l == 0) { nred[w] = numSum; cred[w] = cnt; }

    // ---- column registers: col[i] = {expT[hw+i][l], expT[hw+i][64+l]} ----
    v2f col[64];
    #pragma unroll
    for (int i = 0; i < 64; ++i) {
        col[i].x = __expf(trans[(hw + i) * NT + l]);
        col[i].y = __expf(trans[(hw + i) * NT + 64 + l]);
    }

    // ---- alpha_0: lane i of wave w holds alpha[hw+i] ----
    float aO = __expf(startT[hw + l] + em_b[hw + l]);

    // ---- em pipeline (own half only): slot s holds em[t=s+1 (mod 8)][hw+l] ----
    const float* emj = em_b + hw + l;
    float rE0 = emj[1 * NT], rE1 = emj[2 * NT], rE2 = emj[3 * NT], rE3 = emj[4 * NT];
    float rE4 = emj[5 * NT], rE5 = emj[6 * NT], rE6 = emj[7 * NT], rE7 = emj[8 * NT];

    __syncthreads();   // maskv + nred visible; one-time full barrier

#define STEP(SL, T, RN)                                                      \
  {                                                                          \
    const int t_   = (T);                                                    \
    const int par_ = t_ & 1;                                                 \
    int   tn_ = (t_ + 8 < S_LEN) ? t_ + 8 : S_LEN - 1;                       \
    float nE_ = emj[(size_t)tn_ * NT];                                       \
    float mv_ = maskv[t_];                                                   \
    float e_  = __expf(rE##SL);                                              \
    rE##SL = nE_;                                                            \
    v2f a0_ = {0.f,0.f}, a1_ = {0.f,0.f}, a2_ = {0.f,0.f}, a3_ = {0.f,0.f};  \
    _Pragma("unroll")                                                        \
    for (int i_ = 0; i_ < 64; i_ += 4) {                                     \
      float s0_ = bcastf(aO, i_);                                            \
      float s1_ = bcastf(aO, i_ + 1);                                        \
      float s2_ = bcastf(aO, i_ + 2);                                        \
      float s3_ = bcastf(aO, i_ + 3);                                        \
      a0_ += (v2f){s0_, s0_} * col[i_];                                      \
      a1_ += (v2f){s1_, s1_} * col[i_ + 1];                                  \
      a2_ += (v2f){s2_, s2_} * col[i_ + 2];                                  \
      a3_ += (v2f){s3_, s3_} * col[i_ + 3];                                  \
    }                                                                        \
    v2f p_ = (a0_ + a1_) + (a2_ + a3_);                                      \
    /* p_.x = partial for j=l (x half), p_.y = partial for j=64+l (y half) */\
    float keep_ = (w == 0) ? p_.x : p_.y;                                    \
    float ship_ = (w == 0) ? p_.y : p_.x;                                    \
    xchg[par_][1 ^ w][l] = ship_;       /* one ds_write_b32 */               \
    lds_barrier();                                                           \
    float oth_  = xchg[par_][w][l];     /* one ds_read_b32 */                \
    float comb_ = (keep_ + oth_) * e_;  /* fold exp(em[own half]) */         \
    aO = (mv_ != 0.0f) ? comb_ : aO;                                         \
    if (RN) aO *= RENORM;                                                    \
  }

    // chunk 0: t = 1..7  (slot = (t-1)&7)
    STEP(0, 1, false) STEP(1, 2, false) STEP(2, 3, false) STEP(3, 4, false)
    STEP(4, 5, false) STEP(5, 6, false) STEP(6, 7, false)

    // chunks 1..63: t = 8c .. 8c+7 ; renorm at t = 8c (63 renorms total)
    for (int c = 1; c < 64; ++c) {
        const int t0 = c * 8;
        STEP(7, t0,     true)
        STEP(0, t0 + 1, false) STEP(1, t0 + 2, false) STEP(2, t0 + 3, false)
        STEP(3, t0 + 4, false) STEP(4, t0 + 5, false) STEP(5, t0 + 6, false)
        STEP(6, t0 + 7, false)
    }
#undef STEP

    // ---- finalize: gather halves, wave 0 computes denominator ----
    aF[hw + l] = aO;
    __syncthreads();

    if (w == 0) {
        float ax = aF[l];
        float ay = aF[64 + l];
        float pe = ax * __expf(endT[l]) + ay * __expf(endT[64 + l]);
        #pragma unroll
        for (int off = 32; off > 0; off >>= 1)
            pe += __shfl_down(pe, off, 64);
        if (l == 0) {
            int   cT   = cred[0] + cred[1];
            int   last = tg_b[cT - 1];
            float num  = nred[0] + nred[1] + endT[last];
            float den  = 63.0f * 62.0f * LN2F + logf(pe);
            atomicAdd(out, (num - den) * (1.0f / (float)B_SZ));
        }
    }
}

extern "C" void kernel_launch(void* const* d_in, const int* in_sizes, int n_in,
                              void* d_out, int out_size, void* d_ws, size_t ws_size,
                              hipStream_t stream) {
    const float* em     = (const float*)d_in[0];
    const int*   tags   = (const int*)d_in[1];
    const float* startT = (const float*)d_in[2];
    const float* endT   = (const float*)d_in[3];
    const float* trans  = (const float*)d_in[4];
    float* out = (float*)d_out;

    hipMemsetAsync(out, 0, sizeof(float), stream);
    crf_fused<<<B_SZ, 128, 0, stream>>>(em, tags, startT, endT, trans, out);
}